// Round 9
// baseline (19.352 us; speedup 1.0000x reference)
//
#include <hip/hip_runtime.h>
#include <math.h>

#define BN_EPS 1e-5f
#define LWIN   193     // 256 - 64 + 1 windows
#define WPB    16      // windows per block
#define NBL    13      // ceil(193/16)
#define SLOC   96      // local sequence positions per block (79 real + halo)
#define STR    97      // LDS row stride for phase arrays

__device__ __forceinline__ float elu(float x) { return x > 0.f ? x : expm1f(x); }

// r5 structure (best: 15.5us) with the U phase de-LDS'd:
//  - eeg read directly from global (coalesced per-wave, L2-resident) with
//    per-element clamped edge positions (bit-identical values to r5 staging).
//  - w2 rows read via wave-uniform SGPR base (readfirstlane) -> s_load on the
//    scalar pipe; no w2 LDS copy.
// Removes the DMA staging phase + 1 barrier + ~770 DS instrs/block from the
// shared LDS pipe. All phases E..Y2 are r5 VERBATIM (validated absmax 0.0).
// Phases: fold+U | E | P2 | Q | Ef | S5 | Y1 | Y2   (7 barriers).
__global__ __launch_bounds__(256) void eegnet_fused(
    const float* __restrict__ eeg,
    const float* __restrict__ c1w, const float* __restrict__ c1b,
    const float* __restrict__ bn1g, const float* __restrict__ bn1b,
    const float* __restrict__ bn1m, const float* __restrict__ bn1v,
    const float* __restrict__ w2,  const float* __restrict__ c2b,
    const float* __restrict__ bn2g, const float* __restrict__ bn2b,
    const float* __restrict__ bn2m, const float* __restrict__ bn2v,
    const float* __restrict__ c3w, const float* __restrict__ c3b,
    const float* __restrict__ c4w, const float* __restrict__ c4b,
    const float* __restrict__ bn3g, const float* __restrict__ bn3b,
    const float* __restrict__ bn3m, const float* __restrict__ bn3v,
    const float* __restrict__ linw, const float* __restrict__ linb,
    float* __restrict__ out)
{
    const int b   = blockIdx.x;
    const int L0  = blockIdx.y * WPB;
    const int g0  = L0 - 3;
    const int tid = threadIdx.x;
    const int lane16 = tid & 15;
    const int grp16  = tid >> 4;

    __shared__ float Ul[16][STR], El[16][STR], P2[16][STR], Ql[16][STR];
    __shared__ float Ef[16][STR], S5[16][STR];
    __shared__ float cs[512];            // folded constants (layout as r5)
    __shared__ float q0s[16][17], q1s[16][17];

    const float* ebase = eeg + b * 64 * 256;

    // ---- fold constants (parallel across waves; overlaps U's load latency) ----
    if (tid < 64) {
        const int f = tid & 15, q = tid >> 4;
        float s2p = 0.f;
        #pragma unroll
        for (int k = 0; k < 16; ++k) s2p += w2[f * 64 + q * 16 + k];
        s2p += __shfl_xor(s2p, 16);
        s2p += __shfl_xor(s2p, 32);
        if (tid < 16) {
            const int g = f >> 1;
            const float s1 = bn1g[g] / sqrtf(bn1v[g] + BN_EPS);
            const float o1 = bn1b[g] - bn1m[g] * s1;
            const float s2 = bn2g[f] / sqrtf(bn2v[f] + BN_EPS);
            const float o2 = bn2b[f] - bn2m[f] * s2;
            const float ss = s2 * s1;
            cs[      f] = ss * c1w[g * 3 + 0];
            cs[ 16 + f] = ss * c1w[g * 3 + 1];
            cs[ 32 + f] = ss * c1w[g * 3 + 2];
            cs[ 48 + f] = s2 * (fmaf(s1, c1b[g], o1) * s2p + c2b[f]) + o2;
            cs[ 64 + f] = c3w[f * 3 + 0];
            cs[ 80 + f] = c3w[f * 3 + 1];
            cs[ 96 + f] = c3w[f * 3 + 2];
            cs[112 + f] = c3b[f];
        }
    } else if (tid < 128) {
        const int j = tid - 64, f = j & 15, quad = j >> 4;
        const float s3 = bn3g[f] / sqrtf(bn3v[f] + BN_EPS);
        if (quad == 0)
            cs[128 + f] = fmaf(s3, c4b[f], bn3b[f] - bn3m[f] * s3);
        #pragma unroll
        for (int k = 0; k < 4; ++k) {
            const int o = quad * 4 + k;
            cs[144 + o * 16 + f] = s3 * c4w[f * 16 + o];
        }
    } else if (tid < 224) {
        cs[400 + tid - 128] = linw[tid - 128];
    } else if (tid == 224) {
        cs[496] = linb[0];
    }

    // ---- U phase: global eeg loads (coalesced) + scalar w2 loads ----
    {
        const int p  = tid & 63;
        const int og = __builtin_amdgcn_readfirstlane(tid >> 6);   // SGPR
        const int o0 = og * 4;
        const float* wr0 = w2 + (o0    ) * 64;   // SGPR bases -> s_load
        const float* wr1 = w2 + (o0 + 1) * 64;
        const float* wr2 = w2 + (o0 + 2) * 64;
        const float* wr3 = w2 + (o0 + 3) * 64;
        int s1 = g0 + p;       s1 = s1 < 0 ? 0 : (s1 > 255 ? 255 : s1);
        int s2 = g0 + p + 64;  s2 = s2 < 0 ? 0 : (s2 > 255 ? 255 : s2);
        const bool two = (p < 32);       // lanes 0..31 also do position p+64
        float a0 = 0.f, a1 = 0.f, a2 = 0.f, a3 = 0.f;
        float b0 = 0.f, b1 = 0.f, b2 = 0.f, b3 = 0.f;
        #pragma unroll 8
        for (int c = 0; c < 64; ++c) {
            const float e   = ebase[c * 256 + s1];
            const float w0c = wr0[c], w1c = wr1[c], w2c = wr2[c], w3c = wr3[c];
            a0 = fmaf(w0c, e, a0); a1 = fmaf(w1c, e, a1);
            a2 = fmaf(w2c, e, a2); a3 = fmaf(w3c, e, a3);
            if (two) {
                const float e2 = ebase[c * 256 + s2];
                b0 = fmaf(w0c, e2, b0); b1 = fmaf(w1c, e2, b1);
                b2 = fmaf(w2c, e2, b2); b3 = fmaf(w3c, e2, b3);
            }
        }
        Ul[o0    ][p] = a0; Ul[o0 + 1][p] = a1;
        Ul[o0 + 2][p] = a2; Ul[o0 + 3][p] = a3;
        if (two) {
            Ul[o0    ][p + 64] = b0; Ul[o0 + 1][p + 64] = b1;
            Ul[o0 + 2][p + 64] = b2; Ul[o0 + 3][p + 64] = b3;
        }
    }
    __syncthreads();   // Ul + cs ready

    // ---- E phase (global zero-pad at s=0 / s=255) ----
    #pragma unroll
    for (int k = 0; k < 6; ++k) {
        const int i = grp16 + 16 * k, sg = g0 + i, o = lane16;
        const float um = (sg >= 1)   ? Ul[o][i > 0 ? i - 1 : 0] : 0.f;
        const float uc = Ul[o][i];
        const float up = (sg <= 254) ? Ul[o][i < SLOC - 1 ? i + 1 : SLOC - 1] : 0.f;
        El[o][i] = elu(fmaf(cs[o], um, fmaf(cs[16 + o], uc, fmaf(cs[32 + o], up, cs[48 + o]))));
    }
    __syncthreads();

    // ---- P2 phase ----
    #pragma unroll
    for (int k = 0; k < 6; ++k) {
        const int i = grp16 + 16 * k, o = lane16;
        const int ip = i < SLOC - 1 ? i + 1 : SLOC - 1;
        P2[o][i] = 0.5f * (El[o][i] + El[o][ip]);
    }
    __syncthreads();

    // ---- Q phase ----
    #pragma unroll
    for (int k = 0; k < 6; ++k) {
        const int i = grp16 + 16 * k, o = lane16;
        const int im = i >= 2 ? i - 2 : 0;
        const int ip = i < SLOC - 2 ? i + 2 : SLOC - 1;
        Ql[o][i] = fmaf(cs[64 + o], P2[o][im],
                   fmaf(cs[80 + o], P2[o][i],
                   fmaf(cs[96 + o], P2[o][ip], cs[112 + o])));
    }
    __syncthreads();

    // ---- Ef phase: 1x1 conv + bn3 + elu ----
    #pragma unroll
    for (int k = 0; k < 6; ++k) {
        const int i = grp16 + 16 * k, f = lane16;
        float r = cs[128 + f];
        #pragma unroll
        for (int o = 0; o < 16; ++o)
            r = fmaf(cs[144 + o * 16 + f], Ql[o][i], r);
        Ef[f][i] = elu(r);
    }
    __syncthreads();

    // ---- S5 phase ----
    #pragma unroll
    for (int k = 0; k < 6; ++k) {
        const int i = grp16 + 16 * k, f = lane16;
        const int i2 = i + 2 < SLOC ? i + 2 : SLOC - 1;
        const int i4 = i + 4 < SLOC ? i + 4 : SLOC - 1;
        const int i6 = i + 6 < SLOC ? i + 6 : SLOC - 1;
        const int i8 = i + 8 < SLOC ? i + 8 : SLOC - 1;
        S5[f][i] = Ef[f][i] + Ef[f][i2] + Ef[f][i4] + Ef[f][i6] + Ef[f][i8];
    }
    __syncthreads();

    // ---- Y1: per-window edge-corrected q0/q1 ----
    {
        const int w = grp16, o = lane16, l = L0 + w;
        if (l < LWIN) {
            const int li = w + 3;
            const float z0 = fmaf(cs[16 + o], Ul[o][li], fmaf(cs[32 + o], Ul[o][li + 1], cs[48 + o]));
            const float P0 = 0.5f * (elu(z0) + El[o][li + 1]);
            const float pa = P2[o][li + 2], pb = P2[o][li + 4];
            q0s[w][o] = fmaf(cs[80 + o], P0, fmaf(cs[96 + o], pa, cs[112 + o]));
            q1s[w][o] = fmaf(cs[64 + o], P0, fmaf(cs[80 + o], pa, fmaf(cs[96 + o], pb, cs[112 + o])));
        }
    }
    __syncthreads();

    // ---- Y2: per-window output, reduce over f ----
    {
        const int w = grp16, f = lane16, l = L0 + w;
        float part = 0.f;
        if (l < LWIN) {
            const int li = w + 3;
            float r0 = cs[128 + f], r1 = r0;
            #pragma unroll
            for (int o = 0; o < 16; ++o) {
                const float wt = cs[144 + o * 16 + f];
                r0 = fmaf(wt, q0s[w][o], r0);
                r1 = fmaf(wt, q1s[w][o], r1);
            }
            part = cs[400 + f * 6] * (elu(r0) + elu(r1) - Ef[f][li] - Ef[f][li + 2]);
            #pragma unroll
            for (int g = 0; g < 6; ++g)
                part = fmaf(cs[400 + f * 6 + g], S5[f][li + 10 * g], part);
        }
        part += __shfl_xor(part, 1);
        part += __shfl_xor(part, 2);
        part += __shfl_xor(part, 4);
        part += __shfl_xor(part, 8);
        if (f == 0 && l < LWIN) out[b * LWIN + l] = fmaf(0.2f, part, cs[496]);
    }
}

extern "C" void kernel_launch(void* const* d_in, const int* in_sizes, int n_in,
                              void* d_out, int out_size, void* d_ws, size_t ws_size,
                              hipStream_t stream) {
    const float* eeg  = (const float*)d_in[0];
    // d_in[1] = env, unused by the reference computation
    const float* c1w  = (const float*)d_in[2];
    const float* c1b  = (const float*)d_in[3];
    const float* bn1g = (const float*)d_in[4];
    const float* bn1b = (const float*)d_in[5];
    const float* bn1m = (const float*)d_in[6];
    const float* bn1v = (const float*)d_in[7];
    const float* w2   = (const float*)d_in[8];
    const float* c2b  = (const float*)d_in[9];
    const float* bn2g = (const float*)d_in[10];
    const float* bn2b = (const float*)d_in[11];
    const float* bn2m = (const float*)d_in[12];
    const float* bn2v = (const float*)d_in[13];
    const float* c3w  = (const float*)d_in[14];
    const float* c3b  = (const float*)d_in[15];
    const float* c4w  = (const float*)d_in[16];
    const float* c4b  = (const float*)d_in[17];
    const float* bn3g = (const float*)d_in[18];
    const float* bn3b = (const float*)d_in[19];
    const float* bn3m = (const float*)d_in[20];
    const float* bn3v = (const float*)d_in[21];
    const float* linw = (const float*)d_in[22];
    const float* linb = (const float*)d_in[23];

    eegnet_fused<<<dim3(16, NBL), 256, 0, stream>>>(
        eeg, c1w, c1b, bn1g, bn1b, bn1m, bn1v, w2, c2b,
        bn2g, bn2b, bn2m, bn2v, c3w, c3b, c4w, c4b,
        bn3g, bn3b, bn3m, bn3v, linw, linb, (float*)d_out);
}

// Round 10
// 16.397 us; speedup vs baseline: 1.1802x; 1.1802x over previous
//
#include <hip/hip_runtime.h>
#include <math.h>

#define BN_EPS 1e-5f
#define LWIN   193     // 256 - 64 + 1 windows
#define WPB    16      // windows per block
#define NBL    13      // ceil(193/16)
#define SLOC   96      // local sequence positions per block (79 real + halo)
#define STR    97      // LDS row stride for phase arrays

typedef __attribute__((address_space(1))) const unsigned int gl_u32;
typedef __attribute__((address_space(3))) unsigned int lds_u32;

__device__ __forceinline__ float elu(float x) { return x > 0.f ? x : expm1f(x); }

// r5 data placement (best: 15.5us) + wave-channel-ownership scheduling:
// wave og owns channels/filters 4og..4og+3 through U->E->P2->Q and Ef->S5,
// so those phases need NO block barriers (same-wave LDS deps only; compiler
// inserts lgkmcnt). Barriers: 8 -> 3. Per-element math is r5 VERBATIM
// (validated absmax 0.0): identical formulas, clamps, FP order.
// Phases: stage+fold | B1 | U E P2 Q | B2 | Ef S5 Y1 | B3 | Y2.
__global__ __launch_bounds__(256) void eegnet_fused(
    const float* __restrict__ eeg,
    const float* __restrict__ c1w, const float* __restrict__ c1b,
    const float* __restrict__ bn1g, const float* __restrict__ bn1b,
    const float* __restrict__ bn1m, const float* __restrict__ bn1v,
    const float* __restrict__ w2,  const float* __restrict__ c2b,
    const float* __restrict__ bn2g, const float* __restrict__ bn2b,
    const float* __restrict__ bn2m, const float* __restrict__ bn2v,
    const float* __restrict__ c3w, const float* __restrict__ c3b,
    const float* __restrict__ c4w, const float* __restrict__ c4b,
    const float* __restrict__ bn3g, const float* __restrict__ bn3b,
    const float* __restrict__ bn3m, const float* __restrict__ bn3v,
    const float* __restrict__ linw, const float* __restrict__ linb,
    float* __restrict__ out)
{
    const int b    = blockIdx.x;
    const int L0   = blockIdx.y * WPB;
    const int g0   = L0 - 3;
    const int tid  = threadIdx.x;
    const int lane = tid & 63;
    const int og   = tid >> 6;       // wave id 0..3, owns channels 4og..4og+3
    const int o0   = og * 4;
    const int lane16 = tid & 15;
    const int grp16  = tid >> 4;

    __shared__ __align__(16) float Eg[64 * SLOC];  // eeg slice, stride 96
    __shared__ float4 w2t4[64 * 4];      // [c][og]: w2 transposed, 4 o per float4
    __shared__ float  Ul[16][STR], El[16][STR], P2[16][STR], Ql[16][STR];
    __shared__ float  Ef[16][STR], S5[16][STR];
    __shared__ __align__(16) float cs[512];        // folded constants (r5 layout)
    __shared__ float  q0s[16][17], q1s[16][17];

    const float* ebase = eeg + b * 64 * 256;

    // ---- stage eeg -> LDS: 24 DMA chunks (6/wave); per-element clamped
    //      fallback for edge chunks (r4 lesson) ----
    {
        #pragma unroll
        for (int j = 0; j < 6; ++j) {
            const int n    = og * 6 + j;          // chunk-instr index 0..23
            const int fidx = n * 256 + lane * 4;  // dest float index (lane x 16B)
            const int c    = fidx / SLOC;         // SLOC%4==0 -> chunk in-row
            const int i    = fidx - c * SLOC;
            const int s    = g0 + i;
            if (s >= 0 && s <= 252) {
                __builtin_amdgcn_global_load_lds((gl_u32*)(ebase + c * 256 + s),
                                                 (lds_u32*)&Eg[n * 256], 16, 0, 0);
            } else {
                const float* row = ebase + c * 256;
                const int e0 = s     < 0 ? 0 : (s     > 255 ? 255 : s);
                const int e1 = s + 1 < 0 ? 0 : (s + 1 > 255 ? 255 : s + 1);
                const int e2 = s + 2 < 0 ? 0 : (s + 2 > 255 ? 255 : s + 2);
                const int e3 = s + 3 < 0 ? 0 : (s + 3 > 255 ? 255 : s + 3);
                *reinterpret_cast<float4*>(&Eg[fidx]) =
                    make_float4(row[e0], row[e1], row[e2], row[e3]);
            }
        }
    }

    // ---- w2 -> LDS transposed (wave og writes its own slice) ----
    {
        const int c = lane;
        w2t4[c * 4 + og] = make_float4(w2[(o0    ) * 64 + c], w2[(o0 + 1) * 64 + c],
                                       w2[(o0 + 2) * 64 + c], w2[(o0 + 3) * 64 + c]);
    }

    // ---- fold constants (r5 layout, parallel across waves) ----
    if (tid < 64) {
        const int f = tid & 15, q = tid >> 4;
        float s2p = 0.f;
        #pragma unroll
        for (int k = 0; k < 16; ++k) s2p += w2[f * 64 + q * 16 + k];
        s2p += __shfl_xor(s2p, 16);
        s2p += __shfl_xor(s2p, 32);
        if (tid < 16) {
            const int g = f >> 1;
            const float s1 = bn1g[g] / sqrtf(bn1v[g] + BN_EPS);
            const float o1 = bn1b[g] - bn1m[g] * s1;
            const float s2 = bn2g[f] / sqrtf(bn2v[f] + BN_EPS);
            const float o2 = bn2b[f] - bn2m[f] * s2;
            const float ss = s2 * s1;
            cs[      f] = ss * c1w[g * 3 + 0];
            cs[ 16 + f] = ss * c1w[g * 3 + 1];
            cs[ 32 + f] = ss * c1w[g * 3 + 2];
            cs[ 48 + f] = s2 * (fmaf(s1, c1b[g], o1) * s2p + c2b[f]) + o2;
            cs[ 64 + f] = c3w[f * 3 + 0];
            cs[ 80 + f] = c3w[f * 3 + 1];
            cs[ 96 + f] = c3w[f * 3 + 2];
            cs[112 + f] = c3b[f];
        }
    } else if (tid < 128) {
        const int j = tid - 64, f = j & 15, quad = j >> 4;
        const float s3 = bn3g[f] / sqrtf(bn3v[f] + BN_EPS);
        if (quad == 0)
            cs[128 + f] = fmaf(s3, c4b[f], bn3b[f] - bn3m[f] * s3);
        #pragma unroll
        for (int k = 0; k < 4; ++k) {
            const int o = quad * 4 + k;
            cs[144 + o * 16 + f] = s3 * c4w[f * 16 + o];
        }
    } else if (tid < 224) {
        cs[400 + tid - 128] = linw[tid - 128];
    } else if (tid == 224) {
        cs[496] = linb[0];
    }
    __syncthreads();   // B1: Eg (all waves' DMA) + w2t4 + cs ready

    // ---- U phase: wave og owns channels o0..o0+3 (r5 verbatim) ----
    {
        const int p = lane;
        const bool two = (p < 32);
        float a0 = 0.f, a1 = 0.f, a2 = 0.f, a3 = 0.f;
        float b0 = 0.f, b1 = 0.f, b2 = 0.f, b3 = 0.f;
        #pragma unroll 8
        for (int c = 0; c < 64; ++c) {
            const float4 w = w2t4[c * 4 + og];       // ds_read_b128, wave-uniform
            const float  e = Eg[c * SLOC + p];       // conflict-free (2-way max)
            a0 = fmaf(w.x, e, a0); a1 = fmaf(w.y, e, a1);
            a2 = fmaf(w.z, e, a2); a3 = fmaf(w.w, e, a3);
            if (two) {
                const float e2 = Eg[c * SLOC + p + 64];
                b0 = fmaf(w.x, e2, b0); b1 = fmaf(w.y, e2, b1);
                b2 = fmaf(w.z, e2, b2); b3 = fmaf(w.w, e2, b3);
            }
        }
        Ul[o0    ][p] = a0; Ul[o0 + 1][p] = a1;
        Ul[o0 + 2][p] = a2; Ul[o0 + 3][p] = a3;
        if (two) {
            Ul[o0    ][p + 64] = b0; Ul[o0 + 1][p + 64] = b1;
            Ul[o0 + 2][p + 64] = b2; Ul[o0 + 3][p + 64] = b3;
        }
    }
    // no block barrier: E reads only this wave's Ul rows (same-wave lgkmcnt)

    // ---- E phase (wave-owned channels; formulas r5-verbatim) ----
    #pragma unroll
    for (int j = 0; j < 4; ++j) {
        const int o = o0 + j;
        #pragma unroll
        for (int h = 0; h < 2; ++h) {
            const int i = lane + 64 * h;
            if (h == 0 || lane < 32) {
                const int sg = g0 + i;
                const float um = (sg >= 1)   ? Ul[o][i > 0 ? i - 1 : 0] : 0.f;
                const float uc = Ul[o][i];
                const float up = (sg <= 254) ? Ul[o][i < SLOC - 1 ? i + 1 : SLOC - 1] : 0.f;
                El[o][i] = elu(fmaf(cs[o], um, fmaf(cs[16 + o], uc, fmaf(cs[32 + o], up, cs[48 + o]))));
            }
        }
    }

    // ---- P2 phase (wave-owned) ----
    #pragma unroll
    for (int j = 0; j < 4; ++j) {
        const int o = o0 + j;
        #pragma unroll
        for (int h = 0; h < 2; ++h) {
            const int i = lane + 64 * h;
            if (h == 0 || lane < 32) {
                const int ip = i < SLOC - 1 ? i + 1 : SLOC - 1;
                P2[o][i] = 0.5f * (El[o][i] + El[o][ip]);
            }
        }
    }

    // ---- Q phase (wave-owned) ----
    #pragma unroll
    for (int j = 0; j < 4; ++j) {
        const int o = o0 + j;
        #pragma unroll
        for (int h = 0; h < 2; ++h) {
            const int i = lane + 64 * h;
            if (h == 0 || lane < 32) {
                const int im = i >= 2 ? i - 2 : 0;
                const int ip = i < SLOC - 2 ? i + 2 : SLOC - 1;
                Ql[o][i] = fmaf(cs[64 + o], P2[o][im],
                           fmaf(cs[80 + o], P2[o][i],
                           fmaf(cs[96 + o], P2[o][ip], cs[112 + o])));
            }
        }
    }
    __syncthreads();   // B2: all channels' Ql visible

    // ---- Ef phase: wave og owns filters f0..f0+3; 16 Ql reads amortized ----
    {
        const float4 k4 = *reinterpret_cast<const float4*>(&cs[128 + o0]);
        float ra0 = k4.x, ra1 = k4.y, ra2 = k4.z, ra3 = k4.w;
        float rb0 = k4.x, rb1 = k4.y, rb2 = k4.z, rb3 = k4.w;
        const bool two = (lane < 32);
        #pragma unroll
        for (int o = 0; o < 16; ++o) {
            const float4 w = *reinterpret_cast<const float4*>(&cs[144 + o * 16 + o0]);
            const float qa = Ql[o][lane];
            ra0 = fmaf(w.x, qa, ra0); ra1 = fmaf(w.y, qa, ra1);
            ra2 = fmaf(w.z, qa, ra2); ra3 = fmaf(w.w, qa, ra3);
            if (two) {
                const float qb = Ql[o][lane + 64];
                rb0 = fmaf(w.x, qb, rb0); rb1 = fmaf(w.y, qb, rb1);
                rb2 = fmaf(w.z, qb, rb2); rb3 = fmaf(w.w, qb, rb3);
            }
        }
        Ef[o0    ][lane] = elu(ra0); Ef[o0 + 1][lane] = elu(ra1);
        Ef[o0 + 2][lane] = elu(ra2); Ef[o0 + 3][lane] = elu(ra3);
        if (two) {
            Ef[o0    ][lane + 64] = elu(rb0); Ef[o0 + 1][lane + 64] = elu(rb1);
            Ef[o0 + 2][lane + 64] = elu(rb2); Ef[o0 + 3][lane + 64] = elu(rb3);
        }
    }
    // no block barrier: S5 reads only this wave's Ef rows

    // ---- S5 phase (wave-owned) ----
    #pragma unroll
    for (int j = 0; j < 4; ++j) {
        const int f = o0 + j;
        #pragma unroll
        for (int h = 0; h < 2; ++h) {
            const int i = lane + 64 * h;
            if (h == 0 || lane < 32) {
                const int i2 = i + 2 < SLOC ? i + 2 : SLOC - 1;
                const int i4 = i + 4 < SLOC ? i + 4 : SLOC - 1;
                const int i6 = i + 6 < SLOC ? i + 6 : SLOC - 1;
                const int i8 = i + 8 < SLOC ? i + 8 : SLOC - 1;
                S5[f][i] = Ef[f][i] + Ef[f][i2] + Ef[f][i4] + Ef[f][i6] + Ef[f][i8];
            }
        }
    }

    // ---- Y1: per-window edge-corrected q0/q1 (inputs ready since B2) ----
    {
        const int w = grp16, o = lane16, l = L0 + w;
        if (l < LWIN) {
            const int li = w + 3;
            const float z0 = fmaf(cs[16 + o], Ul[o][li], fmaf(cs[32 + o], Ul[o][li + 1], cs[48 + o]));
            const float P0 = 0.5f * (elu(z0) + El[o][li + 1]);
            const float pa = P2[o][li + 2], pb = P2[o][li + 4];
            q0s[w][o] = fmaf(cs[80 + o], P0, fmaf(cs[96 + o], pa, cs[112 + o]));
            q1s[w][o] = fmaf(cs[64 + o], P0, fmaf(cs[80 + o], pa, fmaf(cs[96 + o], pb, cs[112 + o])));
        }
    }
    __syncthreads();   // B3: Ef/S5 (cross-channel) + q0s/q1s visible

    // ---- Y2: per-window output, reduce over f (r5 verbatim) ----
    {
        const int w = grp16, f = lane16, l = L0 + w;
        float part = 0.f;
        if (l < LWIN) {
            const int li = w + 3;
            float r0 = cs[128 + f], r1 = r0;
            #pragma unroll
            for (int o = 0; o < 16; ++o) {
                const float wt = cs[144 + o * 16 + f];
                r0 = fmaf(wt, q0s[w][o], r0);
                r1 = fmaf(wt, q1s[w][o], r1);
            }
            part = cs[400 + f * 6] * (elu(r0) + elu(r1) - Ef[f][li] - Ef[f][li + 2]);
            #pragma unroll
            for (int g = 0; g < 6; ++g)
                part = fmaf(cs[400 + f * 6 + g], S5[f][li + 10 * g], part);
        }
        part += __shfl_xor(part, 1);
        part += __shfl_xor(part, 2);
        part += __shfl_xor(part, 4);
        part += __shfl_xor(part, 8);
        if (f == 0 && l < LWIN) out[b * LWIN + l] = fmaf(0.2f, part, cs[496]);
    }
}

extern "C" void kernel_launch(void* const* d_in, const int* in_sizes, int n_in,
                              void* d_out, int out_size, void* d_ws, size_t ws_size,
                              hipStream_t stream) {
    const float* eeg  = (const float*)d_in[0];
    // d_in[1] = env, unused by the reference computation
    const float* c1w  = (const float*)d_in[2];
    const float* c1b  = (const float*)d_in[3];
    const float* bn1g = (const float*)d_in[4];
    const float* bn1b = (const float*)d_in[5];
    const float* bn1m = (const float*)d_in[6];
    const float* bn1v = (const float*)d_in[7];
    const float* w2   = (const float*)d_in[8];
    const float* c2b  = (const float*)d_in[9];
    const float* bn2g = (const float*)d_in[10];
    const float* bn2b = (const float*)d_in[11];
    const float* bn2m = (const float*)d_in[12];
    const float* bn2v = (const float*)d_in[13];
    const float* c3w  = (const float*)d_in[14];
    const float* c3b  = (const float*)d_in[15];
    const float* c4w  = (const float*)d_in[16];
    const float* c4b  = (const float*)d_in[17];
    const float* bn3g = (const float*)d_in[18];
    const float* bn3b = (const float*)d_in[19];
    const float* bn3m = (const float*)d_in[20];
    const float* bn3v = (const float*)d_in[21];
    const float* linw = (const float*)d_in[22];
    const float* linb = (const float*)d_in[23];

    eegnet_fused<<<dim3(16, NBL), 256, 0, stream>>>(
        eeg, c1w, c1b, bn1g, bn1b, bn1m, bn1v, w2, c2b,
        bn2g, bn2b, bn2m, bn2v, c3w, c3b, c4w, c4b,
        bn3g, bn3b, bn3m, bn3v, linw, linb, (float*)d_out);
}

// Round 11
// 15.667 us; speedup vs baseline: 1.2352x; 1.0466x over previous
//
#include <hip/hip_runtime.h>
#include <math.h>

#define BN_EPS 1e-5f
#define LWIN   193     // 256 - 64 + 1 windows
#define WPB    16      // windows per block
#define NBL    13      // ceil(193/16)
#define SLOC   96      // local sequence positions per block (79 real + halo)
#define STR    97      // LDS row stride for phase arrays

typedef __attribute__((address_space(1))) const unsigned int gl_u32;
typedef __attribute__((address_space(3))) unsigned int lds_u32;

__device__ __forceinline__ float elu(float x) { return x > 0.f ? x : expm1f(x); }

// FINAL: r5 verbatim — the empirically best structure (15.5us, absmax 0.0).
// Six structural variants (2-kernel split, 512 threads, race-staging,
// global-load U, wave-owned channels, barrier elimination) all regressed;
// the kernel is launch/replay-latency-bound, not pipe-bound.
// Grid: (16 batch, 13 window-chunks), 256 threads (4 waves).
// Block (b, wb) handles windows l in [L0, L0+16), L0 = 16*wb.
// Local coordinate i maps to global sequence position s = g0 + i, g0 = L0-3.
// Staging: in-range 16B chunks via async global_load_lds; edge chunks fall
// back to per-ELEMENT clamped scalar loads (per-chunk clamp would SHIFT data).
__global__ __launch_bounds__(256) void eegnet_fused(
    const float* __restrict__ eeg,
    const float* __restrict__ c1w, const float* __restrict__ c1b,
    const float* __restrict__ bn1g, const float* __restrict__ bn1b,
    const float* __restrict__ bn1m, const float* __restrict__ bn1v,
    const float* __restrict__ w2,  const float* __restrict__ c2b,
    const float* __restrict__ bn2g, const float* __restrict__ bn2b,
    const float* __restrict__ bn2m, const float* __restrict__ bn2v,
    const float* __restrict__ c3w, const float* __restrict__ c3b,
    const float* __restrict__ c4w, const float* __restrict__ c4b,
    const float* __restrict__ bn3g, const float* __restrict__ bn3b,
    const float* __restrict__ bn3m, const float* __restrict__ bn3v,
    const float* __restrict__ linw, const float* __restrict__ linb,
    float* __restrict__ out)
{
    const int b   = blockIdx.x;
    const int L0  = blockIdx.y * WPB;
    const int g0  = L0 - 3;
    const int tid = threadIdx.x;
    const int lane16 = tid & 15;
    const int grp16  = tid >> 4;

    __shared__ __align__(16) float Eg[64 * SLOC];  // eeg slice, linear stride 96
    __shared__ float4 w2t4[64 * 4];      // [c][og]: w2 transposed, 4 o per float4
    __shared__ float  Ul[16][STR];
    __shared__ float  El[16][STR];
    __shared__ float  P2[16][STR];
    __shared__ float  Ql[16][STR];
    __shared__ float  Ef[16][STR];
    __shared__ float  S5[16][STR];
    __shared__ float  cs[512];           // folded constants
    __shared__ float  q0s[16][17], q1s[16][17];

    const float* ebase = eeg + b * 64 * 256;

    // ---- eeg -> LDS: async 16B chunks where fully in-range, else exact
    //      per-element clamped fallback (disjoint LDS slots, no race) ----
    {
        const int wv = tid >> 6, ln = tid & 63;
        #pragma unroll
        for (int j = 0; j < 6; ++j) {
            const int n    = wv * 6 + j;          // chunk-instr index 0..23
            const int fidx = n * 256 + ln * 4;    // dest float index (lane x 16B)
            const int c    = fidx / SLOC;         // SLOC % 4 == 0 -> chunks stay in-row
            const int i    = fidx - c * SLOC;
            const int s    = g0 + i;
            if (s >= 0 && s <= 252) {
                __builtin_amdgcn_global_load_lds((gl_u32*)(ebase + c * 256 + s),
                                                 (lds_u32*)&Eg[n * 256], 16, 0, 0);
            } else {
                const float* row = ebase + c * 256;
                const int e0 = s     < 0 ? 0 : (s     > 255 ? 255 : s);
                const int e1 = s + 1 < 0 ? 0 : (s + 1 > 255 ? 255 : s + 1);
                const int e2 = s + 2 < 0 ? 0 : (s + 2 > 255 ? 255 : s + 2);
                const int e3 = s + 3 < 0 ? 0 : (s + 3 > 255 ? 255 : s + 3);
                *reinterpret_cast<float4*>(&Eg[fidx]) =
                    make_float4(row[e0], row[e1], row[e2], row[e3]);
            }
        }
    }

    // ---- w2 -> LDS transposed ----
    {
        const int og = tid >> 6, c = tid & 63, o0 = og * 4;
        w2t4[c * 4 + og] = make_float4(w2[(o0    ) * 64 + c], w2[(o0 + 1) * 64 + c],
                                       w2[(o0 + 2) * 64 + c], w2[(o0 + 3) * 64 + c]);
    }

    // ---- fold constants, parallel across waves ----
    // cs[0]A cs[16]B cs[32]C cs[48]K | cs[64]w30 cs[80]w31 cs[96]w32 cs[112]b3
    // cs[128]K4 | cs[144+o*16+f]=s3[f]*w4[f][o] | cs[400]lw[96] cs[496]lb
    if (tid < 64) {
        const int f = tid & 15, q = tid >> 4;
        float s2p = 0.f;
        #pragma unroll
        for (int k = 0; k < 16; ++k) s2p += w2[f * 64 + q * 16 + k];
        s2p += __shfl_xor(s2p, 16);
        s2p += __shfl_xor(s2p, 32);
        if (tid < 16) {
            const int g = f >> 1;
            const float s1 = bn1g[g] / sqrtf(bn1v[g] + BN_EPS);
            const float o1 = bn1b[g] - bn1m[g] * s1;
            const float s2 = bn2g[f] / sqrtf(bn2v[f] + BN_EPS);
            const float o2 = bn2b[f] - bn2m[f] * s2;
            const float ss = s2 * s1;
            cs[      f] = ss * c1w[g * 3 + 0];
            cs[ 16 + f] = ss * c1w[g * 3 + 1];
            cs[ 32 + f] = ss * c1w[g * 3 + 2];
            cs[ 48 + f] = s2 * (fmaf(s1, c1b[g], o1) * s2p + c2b[f]) + o2;
            cs[ 64 + f] = c3w[f * 3 + 0];
            cs[ 80 + f] = c3w[f * 3 + 1];
            cs[ 96 + f] = c3w[f * 3 + 2];
            cs[112 + f] = c3b[f];
        }
    } else if (tid < 128) {
        const int j = tid - 64, f = j & 15, quad = j >> 4;
        const float s3 = bn3g[f] / sqrtf(bn3v[f] + BN_EPS);
        if (quad == 0)
            cs[128 + f] = fmaf(s3, c4b[f], bn3b[f] - bn3m[f] * s3);
        #pragma unroll
        for (int k = 0; k < 4; ++k) {
            const int o = quad * 4 + k;
            cs[144 + o * 16 + f] = s3 * c4w[f * 16 + o];
        }
    } else if (tid < 224) {
        cs[400 + tid - 128] = linw[tid - 128];
    } else if (tid == 224) {
        cs[496] = linb[0];
    }
    __syncthreads();   // drains DMA + ds_writes + fold

    // ---- U phase: wave og owns channels o = 4*og..4*og+3 ----
    {
        const int p  = tid & 63;         // position 0..63
        const int og = tid >> 6;         // wave index (uniform) -> w2t4 reads broadcast
        const bool two = (p < 32);       // lanes 0..31 also handle position p+64
        float a0 = 0.f, a1 = 0.f, a2 = 0.f, a3 = 0.f;
        float b0 = 0.f, b1 = 0.f, b2 = 0.f, b3 = 0.f;
        #pragma unroll 8
        for (int c = 0; c < 64; ++c) {
            const float4 w = w2t4[c * 4 + og];       // ds_read_b128, wave-uniform
            const float  e = Eg[c * SLOC + p];       // conflict-free (2-way max)
            a0 = fmaf(w.x, e, a0); a1 = fmaf(w.y, e, a1);
            a2 = fmaf(w.z, e, a2); a3 = fmaf(w.w, e, a3);
            if (two) {
                const float e2 = Eg[c * SLOC + p + 64];
                b0 = fmaf(w.x, e2, b0); b1 = fmaf(w.y, e2, b1);
                b2 = fmaf(w.z, e2, b2); b3 = fmaf(w.w, e2, b3);
            }
        }
        const int o0 = og * 4;
        Ul[o0    ][p] = a0; Ul[o0 + 1][p] = a1;
        Ul[o0 + 2][p] = a2; Ul[o0 + 3][p] = a3;
        if (two) {
            Ul[o0    ][p + 64] = b0; Ul[o0 + 1][p + 64] = b1;
            Ul[o0 + 2][p + 64] = b2; Ul[o0 + 3][p + 64] = b3;
        }
    }
    __syncthreads();

    // ---- E phase (global zero-pad at s=0 / s=255) ----
    #pragma unroll
    for (int k = 0; k < 6; ++k) {
        const int i = grp16 + 16 * k, sg = g0 + i, o = lane16;
        const float um = (sg >= 1)   ? Ul[o][i > 0 ? i - 1 : 0] : 0.f;
        const float uc = Ul[o][i];
        const float up = (sg <= 254) ? Ul[o][i < SLOC - 1 ? i + 1 : SLOC - 1] : 0.f;
        El[o][i] = elu(fmaf(cs[o], um, fmaf(cs[16 + o], uc, fmaf(cs[32 + o], up, cs[48 + o]))));
    }
    __syncthreads();

    // ---- P2 phase ----
    #pragma unroll
    for (int k = 0; k < 6; ++k) {
        const int i = grp16 + 16 * k, o = lane16;
        const int ip = i < SLOC - 1 ? i + 1 : SLOC - 1;
        P2[o][i] = 0.5f * (El[o][i] + El[o][ip]);
    }
    __syncthreads();

    // ---- Q phase ----
    #pragma unroll
    for (int k = 0; k < 6; ++k) {
        const int i = grp16 + 16 * k, o = lane16;
        const int im = i >= 2 ? i - 2 : 0;
        const int ip = i < SLOC - 2 ? i + 2 : SLOC - 1;
        Ql[o][i] = fmaf(cs[64 + o], P2[o][im],
                   fmaf(cs[80 + o], P2[o][i],
                   fmaf(cs[96 + o], P2[o][ip], cs[112 + o])));
    }
    __syncthreads();

    // ---- Ef phase: 1x1 conv + bn3 + elu ----
    #pragma unroll
    for (int k = 0; k < 6; ++k) {
        const int i = grp16 + 16 * k, f = lane16;
        float r = cs[128 + f];
        #pragma unroll
        for (int o = 0; o < 16; ++o)
            r = fmaf(cs[144 + o * 16 + f], Ql[o][i], r);
        Ef[f][i] = elu(r);
    }
    __syncthreads();

    // ---- S5 phase ----
    #pragma unroll
    for (int k = 0; k < 6; ++k) {
        const int i = grp16 + 16 * k, f = lane16;
        const int i2 = i + 2 < SLOC ? i + 2 : SLOC - 1;
        const int i4 = i + 4 < SLOC ? i + 4 : SLOC - 1;
        const int i6 = i + 6 < SLOC ? i + 6 : SLOC - 1;
        const int i8 = i + 8 < SLOC ? i + 8 : SLOC - 1;
        S5[f][i] = Ef[f][i] + Ef[f][i2] + Ef[f][i4] + Ef[f][i6] + Ef[f][i8];
    }
    __syncthreads();

    // ---- Y1: per-window edge-corrected q0/q1 ----
    {
        const int w = grp16, o = lane16, l = L0 + w;
        if (l < LWIN) {
            const int li = w + 3;
            const float z0 = fmaf(cs[16 + o], Ul[o][li], fmaf(cs[32 + o], Ul[o][li + 1], cs[48 + o]));
            const float P0 = 0.5f * (elu(z0) + El[o][li + 1]);
            const float pa = P2[o][li + 2], pb = P2[o][li + 4];
            q0s[w][o] = fmaf(cs[80 + o], P0, fmaf(cs[96 + o], pa, cs[112 + o]));
            q1s[w][o] = fmaf(cs[64 + o], P0, fmaf(cs[80 + o], pa, fmaf(cs[96 + o], pb, cs[112 + o])));
        }
    }
    __syncthreads();

    // ---- Y2: per-window output, reduce over f ----
    {
        const int w = grp16, f = lane16, l = L0 + w;
        float part = 0.f;
        if (l < LWIN) {
            const int li = w + 3;
            float r0 = cs[128 + f], r1 = r0;
            #pragma unroll
            for (int o = 0; o < 16; ++o) {
                const float wt = cs[144 + o * 16 + f];
                r0 = fmaf(wt, q0s[w][o], r0);
                r1 = fmaf(wt, q1s[w][o], r1);
            }
            part = cs[400 + f * 6] * (elu(r0) + elu(r1) - Ef[f][li] - Ef[f][li + 2]);
            #pragma unroll
            for (int g = 0; g < 6; ++g)
                part = fmaf(cs[400 + f * 6 + g], S5[f][li + 10 * g], part);
        }
        part += __shfl_xor(part, 1);
        part += __shfl_xor(part, 2);
        part += __shfl_xor(part, 4);
        part += __shfl_xor(part, 8);
        if (f == 0 && l < LWIN) out[b * LWIN + l] = fmaf(0.2f, part, cs[496]);
    }
}

extern "C" void kernel_launch(void* const* d_in, const int* in_sizes, int n_in,
                              void* d_out, int out_size, void* d_ws, size_t ws_size,
                              hipStream_t stream) {
    const float* eeg  = (const float*)d_in[0];
    // d_in[1] = env, unused by the reference computation
    const float* c1w  = (const float*)d_in[2];
    const float* c1b  = (const float*)d_in[3];
    const float* bn1g = (const float*)d_in[4];
    const float* bn1b = (const float*)d_in[5];
    const float* bn1m = (const float*)d_in[6];
    const float* bn1v = (const float*)d_in[7];
    const float* w2   = (const float*)d_in[8];
    const float* c2b  = (const float*)d_in[9];
    const float* bn2g = (const float*)d_in[10];
    const float* bn2b = (const float*)d_in[11];
    const float* bn2m = (const float*)d_in[12];
    const float* bn2v = (const float*)d_in[13];
    const float* c3w  = (const float*)d_in[14];
    const float* c3b  = (const float*)d_in[15];
    const float* c4w  = (const float*)d_in[16];
    const float* c4b  = (const float*)d_in[17];
    const float* bn3g = (const float*)d_in[18];
    const float* bn3b = (const float*)d_in[19];
    const float* bn3m = (const float*)d_in[20];
    const float* bn3v = (const float*)d_in[21];
    const float* linw = (const float*)d_in[22];
    const float* linb = (const float*)d_in[23];

    eegnet_fused<<<dim3(16, NBL), 256, 0, stream>>>(
        eeg, c1w, c1b, bn1g, bn1b, bn1m, bn1v, w2, c2b,
        bn2g, bn2b, bn2m, bn2v, c3w, c3b, c4w, c4b,
        bn3g, bn3b, bn3m, bn3v, linw, linb, (float*)d_out);
}